// Round 11
// baseline (9109.139 us; speedup 1.0000x reference)
//
#include <hip/hip_runtime.h>
#include <stdint.h>

// GRU scan, persistent cooperative kernel, round 11.
// = round 8/9 proven agent-scope coherence (write-through h stores
// RELAXED/AGENT, aux=17 read-through staging, relaxed per-wave flags, no
// fences, x prefetch, counted vmcnt) + round 10's skew schedule (XCD fast
// path DELETED — it livelocked round 10):
//   A: wait loF(t) [posted MID-step t-1, preloaded at J] -> B: issue lo-stage
//   C: preload hiF, build ax, issue x(t+1) -> D: vmcnt(6)=lo staged; check
//   hiF(t) [posted end t-1] -> E: issue hi-stage -> F: barrier -> phase1
//   (hi-stage RTT hides under MFMAs) -> G: gates-lo + stores + EARLY logits
//   (rows 0-15) -> H: vmcnt(0), post loF -> I: barrier -> phase2 -> gates-hi
//   + stores + LATE logits (rows 16-31) -> J: vmcnt(0), post hiF, preload loF.
// Anti-race: lo/hi flags gate next-step staging of the exact LDS rows each
// wave last reads before posting (early/late logits split) -> no LDS race.

#define NB 256
#define NT 256
#define TB 1024
#define TT 2048
#define II 12
#define HH 512
#define NCL 32
#define ROWS 32

#define HTILE_B (ROWS * HH * 2)               // 32 KiB per cluster per buffer
#define HBUF_B  ((size_t)NCL * HTILE_B)       // 1 MiB per buffer
#define BAR_OFF ((size_t)2 * HBUF_B)
#define WS_USED (BAR_OFF + (size_t)NCL * 256) // 64 flag words per cluster

#define LDSB (ROWS * 1024)                    // 32 KiB A-tile

#define GAS __attribute__((address_space(1)))
#define LAS __attribute__((address_space(3)))

typedef _Float16 half8 __attribute__((ext_vector_type(8)));
typedef float    f32x4 __attribute__((ext_vector_type(4)));

static __device__ __forceinline__ float fast_sigmoid(float x) {
  float e = exp2f(-1.44269504f * x);
  return __builtin_amdgcn_rcpf(1.0f + e);
}
static __device__ __forceinline__ float fast_tanh(float x) {
  float e = exp2f(2.88539008f * x);           // exp(2x)
  return 1.0f - 2.0f * __builtin_amdgcn_rcpf(1.0f + e);
}

// Blocking poll of 32 per-wave flag words, lane-parallel, relaxed agent.
static __device__ __forceinline__ void wait_flags32(unsigned* f, unsigned tgt,
                                                    int* dead) {
  const int l = threadIdx.x & 63;
  long spin = 0;
  for (;;) {
    unsigned v = __hip_atomic_load(f + (l & 31), __ATOMIC_RELAXED,
                                   __HIP_MEMORY_SCOPE_AGENT);
    if (__all(v >= tgt)) break;
    if (++spin > (1L << 24)) { *dead = 1; break; }
  }
}

__global__ void __launch_bounds__(NT, 1)
gru_persistent(const float* __restrict__ hist,
               const float* __restrict__ w_ih,
               const float* __restrict__ w_hh,
               const float* __restrict__ w_out,
               const float* __restrict__ b_out,
               float* __restrict__ out,
               uint8_t* __restrict__ ws)
{
  extern __shared__ char smem[];
  char* ldsA = smem;
  const int bid = blockIdx.x;
  const int c   = bid & 31;          // cluster (32)
  const int g   = bid >> 5;          // block within cluster (8)
  const int tid = threadIdx.x;
  const int w   = tid >> 6;          // wave 0..3 -> col-tile
  const int l   = tid & 63;
  const int l15 = l & 15;
  const int l4  = l >> 4;
  const int crb = c * ROWS;
  unsigned* loF = (unsigned*)(ws + BAR_OFF) + (size_t)c * 64;  // words 0..31
  unsigned* hiF = loF + 32;                                    // words 32..63
  const int myflag = g * 4 + w;

  const int col0 = g * 64 + w * 16;  // wave's 16 output cols
  const int pcol = col0 + l15;

  // ---- W_hh register B-fragments for r,z,n (16 K-slices each, static idx)
  half8 wr[16], wz[16], wn[16];
#pragma unroll
  for (int ks = 0; ks < 16; ++ks) {
    const size_t Rr = (size_t)(0 * HH + col0 + l15) * HH + ks * 32 + l4 * 8;
    const size_t Rz = (size_t)(1 * HH + col0 + l15) * HH + ks * 32 + l4 * 8;
    const size_t Rn = (size_t)(2 * HH + col0 + l15) * HH + ks * 32 + l4 * 8;
#pragma unroll
    for (int i = 0; i < 8; ++i) {
      wr[ks][i] = (_Float16)w_hh[Rr + i];
      wz[ks][i] = (_Float16)w_hh[Rz + i];
      wn[ks][i] = (_Float16)w_hh[Rn + i];
    }
  }

  // ---- w_ih register B-fragments (K window = x cols 0..31)
  half8 wih[3];
#pragma unroll
  for (int gt = 0; gt < 3; ++gt) {
    const int R = gt * HH + col0 + l15;
#pragma unroll
    for (int i = 0; i < 8; ++i) {
      const int k = l4 * 8 + i;
      wih[gt][i] = (_Float16)((k < II) ? w_ih[R * II + k] : 0.0f);
    }
  }

  // ---- logits: wave myflag -> early row erow, late row 16+erow, output jj
  //      lane l holds w_out[jj][l*8 .. l*8+7]; full 64-lane reduce
  const int jj   = myflag & 1;
  const int erow = myflag >> 1;
  float wor8[8];
#pragma unroll
  for (int i = 0; i < 8; ++i) wor8[i] = w_out[jj * HH + l * 8 + i];
  const float bo = b_out[jj];

  float hprev[2][4];
#pragma unroll
  for (int mt = 0; mt < 2; ++mt)
#pragma unroll
    for (int q = 0; q < 4; ++q) hprev[mt][q] = 0.0f;

  int deadlock = 0;

  // ---- x prologue: prefetch x(0); drain so the loop ledger starts clean
  f32x4 xn0[2], xn1[2];
#pragma unroll
  for (int mt = 0; mt < 2; ++mt) {
    xn0[mt] = (f32x4){0.f, 0.f, 0.f, 0.f};
    xn1[mt] = (f32x4){0.f, 0.f, 0.f, 0.f};
    const float* xp = hist + (size_t)(crb + mt * 16 + l15) * (TT * II);
    if (l4 == 0)      { xn0[mt] = *(const f32x4*)xp; xn1[mt] = *(const f32x4*)(xp + 4); }
    else if (l4 == 1) { xn0[mt] = *(const f32x4*)(xp + 8); }
  }
  asm volatile("s_waitcnt vmcnt(0)" ::: "memory");

  unsigned preLo = 0, preHi = 0;

  for (int t = 0; t < TT; ++t) {
    const uint8_t* hsrc = ws + ((t & 1) ? HBUF_B : 0) + (size_t)c * HTILE_B;
    uint8_t*       hdst = ws + ((t & 1) ? 0 : HBUF_B) + (size_t)c * HTILE_B;

    // A: wait LO flags of h(t) (posted MID-step t-1; preloaded at J)
    if (t > 0) {
      if (!__all(preLo >= (unsigned)t)) wait_flags32(loF, (unsigned)t, &deadlock);
    }
    __builtin_amdgcn_sched_barrier(0);

    // B: issue lo-stage rows 0-15                                   [out: 4]
#pragma unroll
    for (int it = 0; it < 4; ++it)
      __builtin_amdgcn_global_load_lds(
          (const GAS uint32_t*)(hsrc + it * 4096 + tid * 16),
          (LAS uint32_t*)(ldsA + it * 4096 + tid * 16), 16, 0, 17);
    __builtin_amdgcn_sched_barrier(0);

    // C: preload HI flags (+1); build ax; issue x(t+1) (+6)        [out: 11]
    preHi = __hip_atomic_load(hiF + (l & 31), __ATOMIC_RELAXED,
                              __HIP_MEMORY_SCOPE_AGENT);
    __builtin_amdgcn_sched_barrier(0);
    half8 ax[2];
#pragma unroll
    for (int mt = 0; mt < 2; ++mt)
#pragma unroll
      for (int i = 0; i < 4; ++i) {
        ax[mt][i]     = (_Float16)xn0[mt][i];
        ax[mt][4 + i] = (_Float16)xn1[mt][i];
      }
    {
      const int tx = (t + 1 < TT) ? (t + 1) : 0;
#pragma unroll
      for (int mt = 0; mt < 2; ++mt) {
        const float* xp = hist + (size_t)(crb + mt * 16 + l15) * (TT * II) + (size_t)tx * II;
        if (l4 == 0)      { xn0[mt] = *(const f32x4*)xp; xn1[mt] = *(const f32x4*)(xp + 4); }
        else if (l4 == 1) { xn0[mt] = *(const f32x4*)(xp + 8); }
      }
    }
    __builtin_amdgcn_sched_barrier(0);

    // D: vmcnt(6) -> lo4 + preHi retired (x6 outstanding); check HI flags
    asm volatile("s_waitcnt vmcnt(6)" ::: "memory");
    __builtin_amdgcn_sched_barrier(0);
    if (t > 0 && !__all(preHi >= (unsigned)t)) wait_flags32(hiF, (unsigned)t, &deadlock);
    __builtin_amdgcn_sched_barrier(0);

    // E: issue hi-stage rows 16-31 (RTT hides under phase1)  [out: x6 + hi4]
#pragma unroll
    for (int it = 0; it < 4; ++it)
      __builtin_amdgcn_global_load_lds(
          (const GAS uint32_t*)(hsrc + 16384 + it * 4096 + tid * 16),
          (LAS uint32_t*)(ldsA + 16384 + it * 4096 + tid * 16), 16, 0, 17);
    __builtin_amdgcn_sched_barrier(0);

    // F: barrier -> phase1 may read rows 0-15
    __builtin_amdgcn_s_barrier();
    __builtin_amdgcn_sched_barrier(0);

    // ======== phase 1: rows 0-15 (mt=0) ========
    f32x4 acc0 = (f32x4){0.f, 0.f, 0.f, 0.f};
    f32x4 acc1 = acc0, acc2 = acc0;
    f32x4 accin = __builtin_amdgcn_mfma_f32_16x16x32_f16(ax[0], wih[2],
                    (f32x4){0.f, 0.f, 0.f, 0.f}, 0, 0, 0);
    acc0 = __builtin_amdgcn_mfma_f32_16x16x32_f16(ax[0], wih[0], acc0, 0, 0, 0);
    acc1 = __builtin_amdgcn_mfma_f32_16x16x32_f16(ax[0], wih[1], acc1, 0, 0, 0);
#pragma unroll
    for (int ks = 0; ks < 16; ++ks) {
      const int ko = (ks * 64 + l4 * 16) ^ ((l15 & 7) << 4);
      half8 a = *(const half8*)(ldsA + l15 * 1024 + ko);
      acc0 = __builtin_amdgcn_mfma_f32_16x16x32_f16(a, wr[ks], acc0, 0, 0, 0);
      acc1 = __builtin_amdgcn_mfma_f32_16x16x32_f16(a, wz[ks], acc1, 0, 0, 0);
      acc2 = __builtin_amdgcn_mfma_f32_16x16x32_f16(a, wn[ks], acc2, 0, 0, 0);
    }

    // G: gates + stores rows 0-15
#pragma unroll
    for (int q = 0; q < 4; ++q) {
      const int m = l4 * 4 + q;
      const float r  = fast_sigmoid(acc0[q]);
      const float z  = fast_sigmoid(acc1[q]);
      const float n  = fast_tanh(accin[q] + r * acc2[q]);
      const float hn = (1.0f - z) * n + z * hprev[0][q];
      hprev[0][q] = hn;
      __hip_atomic_store(
          (unsigned short*)(hdst + m * 1024 + ((pcol * 2) ^ ((m & 7) << 4))),
          __builtin_bit_cast(unsigned short, (_Float16)hn),
          __ATOMIC_RELAXED, __HIP_MEMORY_SCOPE_AGENT);
    }

    // EARLY logits (t-1): rows 0-15 — last read of these rows before loF post
    if (t > 0) {
      float s = 0.0f;
      half8 hv = *(const half8*)(ldsA + erow * 1024 + ((l * 16) ^ ((erow & 7) << 4)));
#pragma unroll
      for (int i = 0; i < 8; ++i) s += (float)hv[i] * wor8[i];
#pragma unroll
      for (int off = 1; off < 64; off <<= 1) s += __shfl_xor(s, off);
      if (l == 0) out[((size_t)(crb + erow) * TT + (t - 1)) * 2 + jj] = s + bo;
    }
    __builtin_amdgcn_sched_barrier(0);

    // H: drain (x + hi-stage + lo stores) -> post LO flag
    asm volatile("s_waitcnt vmcnt(0)" ::: "memory");
    __builtin_amdgcn_sched_barrier(0);
    if (l == 0)
      __hip_atomic_store(loF + myflag, (unsigned)(t + 1), __ATOMIC_RELAXED,
                         __HIP_MEMORY_SCOPE_AGENT);

    // I: barrier -> phase2 may read rows 16-31 (drained at H)
    __builtin_amdgcn_s_barrier();
    __builtin_amdgcn_sched_barrier(0);

    // ======== phase 2: rows 16-31 (mt=1) ========
    acc0 = (f32x4){0.f, 0.f, 0.f, 0.f};
    acc1 = acc0; acc2 = acc0;
    accin = __builtin_amdgcn_mfma_f32_16x16x32_f16(ax[1], wih[2],
              (f32x4){0.f, 0.f, 0.f, 0.f}, 0, 0, 0);
    acc0 = __builtin_amdgcn_mfma_f32_16x16x32_f16(ax[1], wih[0], acc0, 0, 0, 0);
    acc1 = __builtin_amdgcn_mfma_f32_16x16x32_f16(ax[1], wih[1], acc1, 0, 0, 0);
#pragma unroll
    for (int ks = 0; ks < 16; ++ks) {
      const int ko = (ks * 64 + l4 * 16) ^ ((l15 & 7) << 4);
      half8 a = *(const half8*)(ldsA + (16 + l15) * 1024 + ko);
      acc0 = __builtin_amdgcn_mfma_f32_16x16x32_f16(a, wr[ks], acc0, 0, 0, 0);
      acc1 = __builtin_amdgcn_mfma_f32_16x16x32_f16(a, wz[ks], acc1, 0, 0, 0);
      acc2 = __builtin_amdgcn_mfma_f32_16x16x32_f16(a, wn[ks], acc2, 0, 0, 0);
    }
#pragma unroll
    for (int q = 0; q < 4; ++q) {
      const int m = 16 + l4 * 4 + q;
      const float r  = fast_sigmoid(acc0[q]);
      const float z  = fast_sigmoid(acc1[q]);
      const float n  = fast_tanh(accin[q] + r * acc2[q]);
      const float hn = (1.0f - z) * n + z * hprev[1][q];
      hprev[1][q] = hn;
      __hip_atomic_store(
          (unsigned short*)(hdst + m * 1024 + ((pcol * 2) ^ ((m & 7) << 4))),
          __builtin_bit_cast(unsigned short, (_Float16)hn),
          __ATOMIC_RELAXED, __HIP_MEMORY_SCOPE_AGENT);
    }

    // LATE logits (t-1): rows 16-31 — last read of these rows before hiF post
    if (t > 0) {
      const int lrw = 16 + erow;
      float s = 0.0f;
      half8 hv = *(const half8*)(ldsA + lrw * 1024 + ((l * 16) ^ ((lrw & 7) << 4)));
#pragma unroll
      for (int i = 0; i < 8; ++i) s += (float)hv[i] * wor8[i];
#pragma unroll
      for (int off = 1; off < 64; off <<= 1) s += __shfl_xor(s, off);
      if (l == 0) out[((size_t)(crb + lrw) * TT + (t - 1)) * 2 + jj] = s + bo;
    }
    __builtin_amdgcn_sched_barrier(0);

    // J: drain -> post HI flag -> preload LO flags for t+1
    asm volatile("s_waitcnt vmcnt(0)" ::: "memory");
    __builtin_amdgcn_sched_barrier(0);
    if (l == 0)
      __hip_atomic_store(hiF + myflag, (unsigned)(t + 1), __ATOMIC_RELAXED,
                         __HIP_MEMORY_SCOPE_AGENT);
    preLo = __hip_atomic_load(loF + (l & 31), __ATOMIC_RELAXED,
                              __HIP_MEMORY_SCOPE_AGENT);
  }

  // ================= epilogue: h(TT) logits + h_final ======================
  asm volatile("s_waitcnt vmcnt(0)" ::: "memory");
  wait_flags32(loF, (unsigned)TT, &deadlock);
  wait_flags32(hiF, (unsigned)TT, &deadlock);
  {
    const uint8_t* hsrc = ws + ((TT & 1) ? HBUF_B : 0) + (size_t)c * HTILE_B;
#pragma unroll
    for (int it = 0; it < 8; ++it)
      __builtin_amdgcn_global_load_lds(
          (const GAS uint32_t*)(hsrc + it * 4096 + tid * 16),
          (LAS uint32_t*)(ldsA + it * 4096 + tid * 16), 16, 0, 17);
    asm volatile("s_waitcnt vmcnt(0)" ::: "memory");
    __builtin_amdgcn_s_barrier();

#pragma unroll
    for (int half = 0; half < 2; ++half) {
      const int lrw = half * 16 + erow;
      float s = 0.0f;
      half8 hv = *(const half8*)(ldsA + lrw * 1024 + ((l * 16) ^ ((lrw & 7) << 4)));
#pragma unroll
      for (int i = 0; i < 8; ++i) s += (float)hv[i] * wor8[i];
#pragma unroll
      for (int off = 1; off < 64; off <<= 1) s += __shfl_xor(s, off);
      if (l == 0) out[((size_t)(crb + lrw) * TT + (TT - 1)) * 2 + jj] = s + bo;
    }
  }

  // ---- h_final from fp32 carried state
#pragma unroll
  for (int mt = 0; mt < 2; ++mt)
#pragma unroll
    for (int q = 0; q < 4; ++q) {
      const int m = mt * 16 + l4 * 4 + q;
      out[(size_t)TB * TT * 2 + (size_t)(crb + m) * HH + pcol] = hprev[mt][q];
    }
}

extern "C" void kernel_launch(void* const* d_in, const int* in_sizes, int n_in,
                              void* d_out, int out_size, void* d_ws, size_t ws_size,
                              hipStream_t stream) {
  (void)in_sizes; (void)n_in; (void)out_size;
  if (ws_size < WS_USED) return;

  const float* hist  = (const float*)d_in[0];
  const float* w_ih  = (const float*)d_in[1];
  const float* w_hh  = (const float*)d_in[2];
  const float* w_out = (const float*)d_in[3];
  const float* b_out = (const float*)d_in[4];
  float* out = (float*)d_out;
  uint8_t* ws = (uint8_t*)d_ws;

  hipMemsetAsync(d_ws, 0, WS_USED, stream);   // h0 = 0, flag words

  void* args[] = {(void*)&hist, (void*)&w_ih, (void*)&w_hh, (void*)&w_out,
                  (void*)&b_out, (void*)&out, (void*)&ws};
  hipError_t e = hipLaunchCooperativeKernel((const void*)gru_persistent,
                                            dim3(NB), dim3(NT), args,
                                            (unsigned)LDSB, stream);
  if (e != hipSuccess) {
    // Fallback: plain launch. 256 blocks at 1/CU on 256 CUs co-reside; every
    // spin loop has a deadlock bail-out so this cannot hang.
    gru_persistent<<<dim3(NB), dim3(NT), LDSB, stream>>>(
        hist, w_ih, w_hh, w_out, b_out, out, ws);
  }
}